// Round 11
// baseline (483.848 us; speedup 1.0000x reference)
//
#include <hip/hip_runtime.h>
#include <hip/hip_bf16.h>

// ---------------------------------------------------------------------------
// MultiHeadAttention block on MI355X (gfx950). Inputs float32 (device-detected,
// kept for robustness). Internal pipeline bf16 MFMA, fp32 accumulate.
// Round-11 changes:
//   * REVERT li2 epilogue to erff. Round-10 post-mortem: tanh-GELU's 2
//     quarter-rate transcendentals (exp+rcp) per value saturate the per-SIMD
//     trans pipe (~4096 cyc/SIMD > K-loop MFMA 2560); ocml erff is a
//     full-rate FMA polynomial. Measured: erff 75us vs gelu_fast 90us.
//   * attn TU=2: two 64-t K/V tiles staged per barrier pair (LDS 32KB,
//     still 4 blocks/CU) -> halves the 64 barrier-drains/block of the
//     latency-bound attention loop. Swizzles identical (verified).
// Workspace (88MB + 32KB):
//   [0,8M) xn/hn  [8,16M) yn/O  [16,24M) WqT,WkT,WvT,li1T  [24,32M) li2T
//   [32,40M) li3T  [40,48M) xout  [48,56M) Qb  [56,72M) KVb  [72,80M) Vt
//   [48,80M) h2 (after attn)  [80,88M) xc  [88M) flag + biases
// ---------------------------------------------------------------------------

typedef __hip_bfloat16 bf16;
typedef __attribute__((ext_vector_type(8))) short  s16x8;
typedef __attribute__((ext_vector_type(4))) short  s16x4;
typedef __attribute__((ext_vector_type(4))) float  f32x4;
typedef __attribute__((ext_vector_type(4))) _Float16 h16x4;

__device__ __forceinline__ float bfbits2f(short s) {
    return __uint_as_float(((unsigned)(unsigned short)s) << 16);
}
__device__ __forceinline__ float load_in(const void* p, size_t i, int f32) {
    return f32 ? ((const float*)p)[i] : bfbits2f(((const short*)p)[i]);
}
// async global->LDS, 16B/lane; lds base wave-uniform, lane i -> base+16i
__device__ __forceinline__ void async16(const short* g, short* l) {
    __builtin_amdgcn_global_load_lds(
        (const __attribute__((address_space(1))) void*)g,
        (__attribute__((address_space(3))) void*)l, 16, 0, 0);
}

// ------------------------- dtype detection ---------------------------------
__global__ __launch_bounds__(256)
void detect_dtype(const short* __restrict__ x, int* __restrict__ flag)
{
    const int tid = threadIdx.x;
    int cnt = 0;
#pragma unroll
    for (int e = 0; e < 16; e++) {
        int idx = (tid * 16 + e) * 2;            // even shorts only
        int ex  = (x[idx] >> 7) & 0xFF;
        if (ex >= 113 && ex <= 142) cnt++;
    }
#pragma unroll
    for (int off = 1; off < 64; off <<= 1) cnt += __shfl_xor(cnt, off, 64);
    __shared__ int sh[4];
    if ((tid & 63) == 0) sh[tid >> 6] = cnt;
    __syncthreads();
    if (tid == 0) {
        int tot = sh[0] + sh[1] + sh[2] + sh[3];  // bf16: ~4096, f32: ~480
        flag[0] = (tot < 2458) ? 1 : 0;           // 1 == inputs are float32
    }
}

// --------------------- conversions / tiled transposes ----------------------
__global__ __launch_bounds__(256)
void conv_bias3(const void* b1, const void* b2, const void* b3,
                bf16* o1, bf16* o2, bf16* o3, const int* __restrict__ flag)
{
    const int f32 = flag[0];
    int i = blockIdx.x * 256 + threadIdx.x;      // 0..6143
    if (i < 1024)      o1[i]        = __float2bfloat16(load_in(b1, i, f32));
    else if (i < 5120) o2[i - 1024] = __float2bfloat16(load_in(b2, i - 1024, f32));
    else               o3[i - 5120] = __float2bfloat16(load_in(b3, i - 5120, f32));
}

// in [R,Cc] -> out [Cc,R], 32x32 LDS tiles, coalesced both sides
__global__ __launch_bounds__(256)
void transpose_tiled(const void* __restrict__ in, bf16* __restrict__ out,
                     int R, int Cc, const int* __restrict__ flag)
{
    __shared__ float tile[32][33];
    const int f32 = flag[0];
    const int tx = threadIdx.x & 31, ty = threadIdx.x >> 5;   // ty 0..7
    const int c0 = blockIdx.x * 32, r0 = blockIdx.y * 32;
#pragma unroll
    for (int i = 0; i < 4; i++)
        tile[ty + i * 8][tx] = load_in(in, (size_t)(r0 + ty + i * 8) * Cc + c0 + tx, f32);
    __syncthreads();
#pragma unroll
    for (int i = 0; i < 4; i++)
        out[(size_t)(c0 + ty + i * 8) * R + r0 + tx] = __float2bfloat16(tile[tx][ty + i * 8]);
}

// Wq [H][C=1024][D=64] -> WqT [H][D][C]  (per-head 1024x64 transpose)
__global__ __launch_bounds__(256)
void pack_qkv_tiled(const void* __restrict__ in, bf16* __restrict__ out,
                    const int* __restrict__ flag)
{
    __shared__ float tile[32][33];
    const int f32 = flag[0];
    const int tx = threadIdx.x & 31, ty = threadIdx.x >> 5;
    const int c0 = blockIdx.x * 32, r0 = blockIdx.y * 32;   // c: D, r: C
    const size_t base = (size_t)blockIdx.z * 1024 * 64;
#pragma unroll
    for (int i = 0; i < 4; i++)
        tile[ty + i * 8][tx] = load_in(in, base + (size_t)(r0 + ty + i * 8) * 64 + c0 + tx, f32);
    __syncthreads();
#pragma unroll
    for (int i = 0; i < 4; i++)
        out[base + (size_t)(c0 + ty + i * 8) * 1024 + r0 + tx] =
            __float2bfloat16(tile[tx][ty + i * 8]);
}

// V part of KVb [b][t][1024+hd] -> Vt [b][hd][t] as f16
__global__ __launch_bounds__(256)
void v_transpose(const bf16* __restrict__ KV, _Float16* __restrict__ Vt)
{
    __shared__ short tile[32][33];
    const int tx = threadIdx.x & 31, ty = threadIdx.x >> 5;
    const int t0 = blockIdx.x * 32, hd0 = blockIdx.y * 32, b = blockIdx.z;
#pragma unroll
    for (int i = 0; i < 4; i++)
        tile[ty + i * 8][tx] =
            ((const short*)KV)[(size_t)(b * 2048 + t0 + ty + i * 8) * 2048 + 1024 + hd0 + tx];
    __syncthreads();
#pragma unroll
    for (int i = 0; i < 4; i++)
        Vt[(size_t)(b * 1024 + hd0 + ty + i * 8) * 2048 + t0 + tx] =
            (_Float16)bfbits2f(tile[tx][ty + i * 8]);
}

// ------------------------------- LayerNorm ---------------------------------
__global__ __launch_bounds__(256)
void ln_kernel(const void* __restrict__ x, const void* __restrict__ w,
               const void* __restrict__ bv, bf16* __restrict__ out,
               const int* __restrict__ flag, int x_is_bf16,
               bf16* __restrict__ copy_out)
{
    const int f32  = flag[0];
    const int xf32 = x_is_bf16 ? 0 : f32;
    const int row  = blockIdx.x;
    const int tid  = threadIdx.x;
    const int lane = tid & 63;
    const int wave = tid >> 6;
    const size_t base = (size_t)row * 1024 + tid * 4;

    float v[4];
    float sum = 0.f, ss = 0.f;
#pragma unroll
    for (int e = 0; e < 4; e++) {
        v[e] = load_in(x, base + e, xf32);
        sum += v[e]; ss += v[e] * v[e];
    }
    if (copy_out) {
        s16x4 c;
#pragma unroll
        for (int e = 0; e < 4; e++) {
            __hip_bfloat16 hb = __float2bfloat16(v[e]);
            c[e] = *(short*)&hb;
        }
        *(s16x4*)((short*)copy_out + base) = c;
    }
#pragma unroll
    for (int off = 1; off < 64; off <<= 1) {
        sum += __shfl_xor(sum, off, 64);
        ss  += __shfl_xor(ss,  off, 64);
    }
    __shared__ float sh1[4], sh2[4];
    if (lane == 0) { sh1[wave] = sum; sh2[wave] = ss; }
    __syncthreads();
    float t1 = sh1[0] + sh1[1] + sh1[2] + sh1[3];
    float t2 = sh2[0] + sh2[1] + sh2[2] + sh2[3];
    float mu   = t1 * (1.f / 1024.f);
    float var  = t2 * (1.f / 1024.f) - mu * mu;
    float rstd = rsqrtf(var + 1e-5f);

#pragma unroll
    for (int e = 0; e < 4; e++) {
        float ov = (v[e] - mu) * rstd * load_in(w, tid * 4 + e, f32)
                 + load_in(bv, tid * 4 + e, f32);
        out[base + e] = __float2bfloat16(ov);
    }
}

// ------------------- GEMM 128x64x(64*KU), swizzled staging -----------------
// KU=2: two 64-wide K-slabs staged per barrier pair (separate LDS buffers,
// identical swizzle) -> 32 MFMA/wave/barrier. ascale folds 1/sqrt(D) into Q.
template<int KU>
__global__ __launch_bounds__(256)
void gemm_bt64(const bf16* __restrict__ A, const bf16* __restrict__ Bt,
               const bf16* __restrict__ bias, const bf16* __restrict__ res,
               void* __restrict__ C, int M, int N, int K, int act,
               const int* __restrict__ dflag, int final_out, float ascale)
{
    __shared__ alignas(16) short As[KU][128][64];
    __shared__ alignas(16) short Bs[KU][64][64];

    const int f32out = final_out ? dflag[0] : 0;
    const int tid  = threadIdx.x;
    const int lane = tid & 63;
    const int wave = tid >> 6;
    const int q    = lane >> 4;
    const int l15  = lane & 15;
    const int wm   = (wave >> 1) * 64;
    const int wn   = (wave & 1) * 32;
    const int bm   = blockIdx.x * 128;
    const int bn   = blockIdx.y * 64;

    const int srow   = lane >> 3;              // 0..7
    const int gchunk = (lane & 7) ^ srow;      // permuted global chunk
    const short* Ab = (const short*)A  + (size_t)(bm + wave * 32 + srow) * K + gchunk * 8;
    const short* Bb = (const short*)Bt + (size_t)(bn + wave * 16 + srow) * K + gchunk * 8;
    const int csw = l15 & 7;

    f32x4 acc[4][2] = {};

    for (int k0 = 0; k0 < K; k0 += 64 * KU) {
        __syncthreads();
#pragma unroll
        for (int u = 0; u < KU; u++) {
            const int ko = k0 + u * 64;
            async16(Ab + ko,                  &As[u][wave * 32][0]);
            async16(Ab + ko + (size_t)8  * K, &As[u][wave * 32 + 8][0]);
            async16(Ab + ko + (size_t)16 * K, &As[u][wave * 32 + 16][0]);
            async16(Ab + ko + (size_t)24 * K, &As[u][wave * 32 + 24][0]);
            async16(Bb + ko,                  &Bs[u][wave * 16][0]);
            async16(Bb + ko + (size_t)8  * K, &Bs[u][wave * 16 + 8][0]);
        }
        __syncthreads();

#pragma unroll
        for (int u = 0; u < KU; u++) {
            s16x8 af[4][2], bfr[2][2];
#pragma unroll
            for (int i = 0; i < 4; i++)
#pragma unroll
                for (int kk = 0; kk < 2; kk++)
                    af[i][kk] = *(const s16x8*)&As[u][wm + i * 16 + l15][((kk * 4 + q) ^ csw) * 8];
#pragma unroll
            for (int j = 0; j < 2; j++)
#pragma unroll
                for (int kk = 0; kk < 2; kk++)
                    bfr[j][kk] = *(const s16x8*)&Bs[u][wn + j * 16 + l15][((kk * 4 + q) ^ csw) * 8];
#pragma unroll
            for (int i = 0; i < 4; i++)
#pragma unroll
                for (int j = 0; j < 2; j++) {
                    acc[i][j] = __builtin_amdgcn_mfma_f32_16x16x32_bf16(af[i][0], bfr[j][0], acc[i][j], 0, 0, 0);
                    acc[i][j] = __builtin_amdgcn_mfma_f32_16x16x32_bf16(af[i][1], bfr[j][1], acc[i][j], 0, 0, 0);
                }
        }
    }

#pragma unroll
    for (int i = 0; i < 4; i++) {
#pragma unroll
        for (int j = 0; j < 2; j++) {
            int n = bn + wn + j * 16 + l15;
            float bvv = bias ? __bfloat162float(bias[n]) : 0.f;
#pragma unroll
            for (int r = 0; r < 4; r++) {
                int m = bm + wm + i * 16 + q * 4 + r;
                float v = acc[i][j][r] * ascale + bvv;
                if (act) v = 0.5f * v * (1.f + erff(v * 0.70710678118f));
                if (res) v += __bfloat162float(res[(size_t)m * N + n]);
                size_t idx = (size_t)m * N + n;
                if (f32out) ((float*)C)[idx] = v;
                else        ((bf16*)C)[idx]  = __float2bfloat16(v);
            }
        }
    }
}

// ------------------- GEMM 128x128x64, swizzled staging (li2) ---------------
__global__ __launch_bounds__(256)
void gemm_bt128(const bf16* __restrict__ A, const bf16* __restrict__ Bt,
                const bf16* __restrict__ bias, const bf16* __restrict__ res,
                void* __restrict__ C, int M, int N, int K, int act,
                const int* __restrict__ dflag, int final_out)
{
    __shared__ alignas(16) short As[128][64];
    __shared__ alignas(16) short Bs[128][64];

    const int f32out = final_out ? dflag[0] : 0;
    const int tid  = threadIdx.x;
    const int lane = tid & 63;
    const int wave = tid >> 6;
    const int q    = lane >> 4;
    const int l15  = lane & 15;
    const int wm   = (wave >> 1) * 64;
    const int wn   = (wave & 1) * 64;
    const int bm   = blockIdx.x * 128;
    const int bn   = blockIdx.y * 128;

    const int srow   = lane >> 3;
    const int gchunk = (lane & 7) ^ srow;
    const short* Ab = (const short*)A  + (size_t)(bm + wave * 32 + srow) * K + gchunk * 8;
    const short* Bb = (const short*)Bt + (size_t)(bn + wave * 32 + srow) * K + gchunk * 8;
    const int csw = l15 & 7;

    f32x4 acc[4][4] = {};

    for (int k0 = 0; k0 < K; k0 += 64) {
        __syncthreads();
#pragma unroll
        for (int r8 = 0; r8 < 4; r8++) {
            async16(Ab + k0 + (size_t)(r8 * 8) * K, &As[wave * 32 + r8 * 8][0]);
            async16(Bb + k0 + (size_t)(r8 * 8) * K, &Bs[wave * 32 + r8 * 8][0]);
        }
        __syncthreads();

#pragma unroll
        for (int kk = 0; kk < 2; kk++) {
            s16x8 af[4], bfr[4];
#pragma unroll
            for (int i = 0; i < 4; i++) af[i]  = *(const s16x8*)&As[wm + i * 16 + l15][((kk * 4 + q) ^ csw) * 8];
#pragma unroll
            for (int j = 0; j < 4; j++) bfr[j] = *(const s16x8*)&Bs[wn + j * 16 + l15][((kk * 4 + q) ^ csw) * 8];
#pragma unroll
            for (int i = 0; i < 4; i++)
#pragma unroll
                for (int j = 0; j < 4; j++)
                    acc[i][j] = __builtin_amdgcn_mfma_f32_16x16x32_bf16(af[i], bfr[j], acc[i][j], 0, 0, 0);
        }
    }

#pragma unroll
    for (int i = 0; i < 4; i++) {
#pragma unroll
        for (int j = 0; j < 4; j++) {
            int n = bn + wn + j * 16 + l15;
            float bvv = bias ? __bfloat162float(bias[n]) : 0.f;
#pragma unroll
            for (int r = 0; r < 4; r++) {
                int m = bm + wm + i * 16 + q * 4 + r;
                float v = acc[i][j][r] + bvv;
                if (act) v = 0.5f * v * (1.f + erff(v * 0.70710678118f));  // full-rate poly
                if (res) v += __bfloat162float(res[(size_t)m * N + n]);
                size_t idx = (size_t)m * N + n;
                if (f32out) ((float*)C)[idx] = v;
                else        ((bf16*)C)[idx]  = __float2bfloat16(v);
            }
        }
    }
}

// ------------------------------ Attention ----------------------------------
// grid (B*H, S/64): dispatch id = stile*32+bh -> id%8 = bh%8, all s-blocks of
// one (b,h) share an XCD; K+V stay L2-resident (round-9 win: FETCH 128->34MB).
// TU=2: two 64-t tiles staged per barrier pair (halves barrier-drain count).
// K from fused KVb (col h*64); V from pre-transposed Vt[b][h*64+d][t] (f16).
// Both staged via global_load_lds w16, unpadded [64][64], chunk-permuted.
// Q pre-scaled by 0.125. Post-softmax mask => l is a pure sum.
__global__ __launch_bounds__(256)
void attn_kernel(const bf16* __restrict__ Q, const bf16* __restrict__ KV,
                 const _Float16* __restrict__ Vt, bf16* __restrict__ O)
{
    __shared__ alignas(16) short    Ks[2][64][64];   // [u][t][d'], chunk-swizzled
    __shared__ alignas(16) _Float16 Vs[2][64][64];   // [u][d][t'], chunk-swizzled

    const int tid  = threadIdx.x;
    const int lane = tid & 63;
    const int wave = tid >> 6;
    const int q    = lane >> 4;
    const int l15  = lane & 15;
    const int bh   = blockIdx.x;                  // XCD key
    const int b    = bh >> 4, h = bh & 15;
    const int sblk   = blockIdx.y * 64;
    const int s_base = sblk + wave * 16;
    const int s_glob = s_base + l15;

    const short* qrow = (const short*)Q + (size_t)(b * 2048 + s_glob) * 1024 + h * 64;
    s16x8 qf0 = *(const s16x8*)(qrow + q * 8);
    s16x8 qf1 = *(const s16x8*)(qrow + 32 + q * 8);

    float l_lane = 0.f;
    f32x4 o_acc[4] = {};

    const int srow = lane >> 3;              // 0..7
    const int gch  = (lane & 7) ^ srow;      // permuted global chunk
    const short*    kbase = (const short*)KV +
        (size_t)(b * 2048 + wave * 16 + srow) * 2048 + h * 64 + gch * 8;
    const _Float16* vbase = Vt +
        (size_t)(b * 1024 + h * 64 + wave * 16 + srow) * 2048 + gch * 8;
    const int key = l15 & 7;                 // frag-read swizzle key

    for (int t0 = 0; t0 < 2048; t0 += 128) {
        __syncthreads();
#pragma unroll
        for (int u = 0; u < 2; u++) {
            const int tt = t0 + u * 64;
            const short* kg = kbase + (size_t)tt * 2048;
            async16(kg,                    &Ks[u][wave * 16][0]);
            async16(kg + (size_t)8 * 2048, &Ks[u][wave * 16 + 8][0]);
            if (tt >= sblk) {
                const _Float16* vg = vbase + tt;
                async16((const short*)vg,                      (short*)&Vs[u][wave * 16][0]);
                async16((const short*)(vg + (size_t)8 * 2048), (short*)&Vs[u][wave * 16 + 8][0]);
            }
        }
        __syncthreads();

#pragma unroll
        for (int u = 0; u < 2; u++) {
#pragma unroll
            for (int sub = 0; sub < 4; sub++) {
                const int tb  = sub * 16;
                const int rel = t0 + u * 64 + tb - s_base;   // wave-uniform
                s16x8 kf0 = *(const s16x8*)&Ks[u][tb + l15][(q ^ key) * 8];
                s16x8 kf1 = *(const s16x8*)&Ks[u][tb + l15][((q + 4) ^ key) * 8];
                f32x4 st = {};
                st = __builtin_amdgcn_mfma_f32_16x16x32_bf16(kf0, qf0, st, 0, 0, 0);
                st = __builtin_amdgcn_mfma_f32_16x16x32_bf16(kf1, qf1, st, 0, 0, 0);
                float p[4];
#pragma unroll
                for (int r = 0; r < 4; r++) {
                    p[r] = __expf(st[r]);
                    l_lane += p[r];
                }
                if (rel >= 0) {
                    h16x4 pf;
                    if (rel == 0) {
#pragma unroll
                        for (int r = 0; r < 4; r++)
                            pf[r] = (q * 4 + r > l15) ? (_Float16)p[r] : (_Float16)0.f;
                    } else {
#pragma unroll
                        for (int r = 0; r < 4; r++) pf[r] = (_Float16)p[r];
                    }
#pragma unroll
                    for (int dt = 0; dt < 4; dt++) {
                        h16x4 vf = *(const h16x4*)&Vs[u][dt * 16 + l15]
                            [(((2 * sub + (q >> 1)) ^ key) * 8) + (q & 1) * 4];
                        o_acc[dt] = __builtin_amdgcn_mfma_f32_16x16x16f16(pf, vf, o_acc[dt], 0, 0, 0);
                    }
                }
            }
        }
    }

    float l = l_lane;
    l += __shfl_xor(l, 16, 64);
    l += __shfl_xor(l, 32, 64);
    float linv[4];
#pragma unroll
    for (int r = 0; r < 4; r++) linv[r] = 1.f / __shfl(l, q * 4 + r, 64);
#pragma unroll
    for (int dt = 0; dt < 4; dt++)
#pragma unroll
        for (int r = 0; r < 4; r++) {
            int s = s_base + q * 4 + r;
            int d = dt * 16 + l15;
            O[(size_t)(b * 2048 + s) * 1024 + h * 64 + d] =
                __float2bfloat16(o_acc[dt][r] * linv[r]);
        }
}

// ------------------------------- launcher ----------------------------------
extern "C" void kernel_launch(void* const* d_in, const int* in_sizes, int n_in,
                              void* d_out, int out_size, void* d_ws, size_t ws_size,
                              hipStream_t stream)
{
    const void* x     = d_in[0];
    const void* y     = d_in[1];
    const void* Wq    = d_in[2];
    const void* Wk    = d_in[3];
    const void* Wv    = d_in[4];
    const void* li1_w = d_in[5];
    const void* li1_b = d_in[6];
    const void* ln1_w = d_in[7];
    const void* ln1_b = d_in[8];
    const void* ln2_w = d_in[9];
    const void* ln2_b = d_in[10];
    const void* ln3_w = d_in[11];
    const void* ln3_b = d_in[12];
    const void* li2_w = d_in[13];
    const void* li2_b = d_in[14];
    const void* li3_w = d_in[15];
    const void* li3_b = d_in[16];

    char* w = (char*)d_ws;
    const size_t MB = 1u << 20;
    bf16* xn    = (bf16*)(w + 0 * MB);
    bf16* yn    = (bf16*)(w + 8 * MB);
    bf16* WqT   = (bf16*)(w + 16 * MB);
    bf16* WkT   = (bf16*)(w + 18 * MB);   // WkT+WvT contiguous = fused KV weights
    bf16* WvT   = (bf16*)(w + 20 * MB);
    bf16* li1T  = (bf16*)(w + 22 * MB);
    bf16* li2T  = (bf16*)(w + 24 * MB);
    bf16* li3T  = (bf16*)(w + 32 * MB);
    bf16* xout  = (bf16*)(w + 40 * MB);
    bf16* Qb    = (bf16*)(w + 48 * MB);
    bf16* KVb   = (bf16*)(w + 56 * MB);   // [4096][2048], 16MB
    _Float16* Vt = (_Float16*)(w + 72 * MB); // [2][1024][2048] f16, 8MB
    bf16* h2    = (bf16*)(w + 48 * MB);   // reuses Qb/KVb/Vt after attention
    bf16* xc    = (bf16*)(w + 80 * MB);   // canonical bf16 copy of x (residual)
    int*  flag  = (int*) (w + 88 * MB);
    bf16* li1bc = (bf16*)(w + 88 * MB + 4096);
    bf16* li2bc = (bf16*)(w + 88 * MB + 8192);
    bf16* li3bc = (bf16*)(w + 88 * MB + 24576);
    bf16* Ob    = yn;                     // reuse yn after KV projection
    bf16* hn    = xn;                     // reuse xn after Q projection

    // 0. dtype detection (deterministic per input -> graph-safe)
    detect_dtype<<<1, 256, 0, stream>>>((const short*)x, flag);

    // 1. biases (single launch)
    conv_bias3<<<24, 256, 0, stream>>>(li1_b, li2_b, li3_b, li1bc, li2bc, li3bc, flag);

    // 2. LayerNorms (LN1 also emits the canonical bf16 copy of x)
    ln_kernel<<<4096, 256, 0, stream>>>(x, ln1_w, ln1_b, xn, flag, 0, xc);
    ln_kernel<<<4096, 256, 0, stream>>>(y, ln2_w, ln2_b, yn, flag, 0, nullptr);

    // 3. weight re-layouts (LDS-tiled, coalesced)
    pack_qkv_tiled<<<dim3(2, 32, 16), 256, 0, stream>>>(Wq, WqT, flag);
    pack_qkv_tiled<<<dim3(2, 32, 16), 256, 0, stream>>>(Wk, WkT, flag);
    pack_qkv_tiled<<<dim3(2, 32, 16), 256, 0, stream>>>(Wv, WvT, flag);
    transpose_tiled<<<dim3(32, 32),  256, 0, stream>>>(li1_w, li1T, 1024, 1024, flag);
    transpose_tiled<<<dim3(128, 32), 256, 0, stream>>>(li2_w, li2T, 1024, 4096, flag);
    transpose_tiled<<<dim3(32, 128), 256, 0, stream>>>(li3_w, li3T, 4096, 1024, flag);

    // 4. projections: Q (pre-scaled by 1/8) and fused KV, then V -> Vt (f16)
    gemm_bt64<2><<<dim3(32, 16), 256, 0, stream>>>(xn, WqT, nullptr, nullptr, Qb, 4096, 1024, 1024, 0, flag, 0, 0.125f);
    gemm_bt64<1><<<dim3(32, 32), 256, 0, stream>>>(yn, WkT, nullptr, nullptr, KVb, 4096, 2048, 1024, 0, flag, 0, 1.0f);
    v_transpose<<<dim3(64, 32, 2), 256, 0, stream>>>(KVb, Vt);

    // 5. attention -> O [B,S,H*D]   (grid x=bh for XCD locality)
    attn_kernel<<<dim3(32, 32), 256, 0, stream>>>(Qb, KVb, Vt, Ob);

    // 6. x_out = x + O @ li1_w + li1_b
    gemm_bt64<2><<<dim3(32, 16), 256, 0, stream>>>(Ob, li1T, li1bc, xc, xout, 4096, 1024, 1024, 0, flag, 0, 1.0f);

    // 7. hn = LN3(x_out)
    ln_kernel<<<4096, 256, 0, stream>>>(xout, ln3_w, ln3_b, hn, flag, 1, nullptr);

    // 8. h2 = gelu(hn @ li2_w + li2_b)   (erff: full-rate polynomial)
    gemm_bt128<<<dim3(32, 32), 256, 0, stream>>>(hn, li2T, li2bc, nullptr, h2, 4096, 4096, 1024, 1, flag, 0);

    // 9. out = x_out + h2 @ li3_w + li3_b   (dtype-matched store)
    gemm_bt64<2><<<dim3(32, 16), 256, 0, stream>>>(h2, li3T, li3bc, xout, d_out, 4096, 1024, 4096, 0, flag, 1, 1.0f);
}